// Round 8
// baseline (504.994 us; speedup 1.0000x reference)
//
#include <hip/hip_runtime.h>
#include <hip/hip_bf16.h>
#include <math.h>

// AtnConv (contextual attention) B=2, H=W=64, C=128, k=3.
// Score path fp32: Ds = skewed X2·X2^T (split-bf16 MFMA, Ds[r][(c-r)&4095],
// vectorized row-wise stores via LDS transpose); invn from skewed col 0;
// G = 9-tap diag stencil read vertically from Ds (float4); Ps = pooled logits
// (skewed) + row softmax stats. Value path bf16: A2 = diag stencil of
// softmax(Ps); Y = A2 @ X1 bf16 MFMA split-K.
// ws: buf1 (Ds->Ps) 64MB; buf2 (X2h/X2l -> G -> A2bf|X1T) 64MB; invn/rowm/rowrz.
// NOTE: k_x1t MUST run after k_pool_stats — X1T at buf2+32MB is clobbered by G.

constexpr int Hh = 64;
constexpr int Ww = 64;
constexpr int CDIM = 128;
constexpr int LDIM = Hh * Ww;   // 4096

typedef __attribute__((ext_vector_type(8))) short bf16x8;
typedef __attribute__((ext_vector_type(4))) float f32x4;

// --------------------------------------------- split X2 into bf16 hi/lo parts
__global__ __launch_bounds__(256)
void k_split(const float* __restrict__ X, __hip_bfloat16* __restrict__ Xh,
             __hip_bfloat16* __restrict__ Xl) {
    const int i = (blockIdx.x * 256 + threadIdx.x) * 4;
    const float4 v = *(const float4*)(X + i);
    __hip_bfloat16 h[4], l[4];
    const float f[4] = {v.x, v.y, v.z, v.w};
    #pragma unroll
    for (int j = 0; j < 4; ++j) {
        h[j] = __float2bfloat16(f[j]);
        l[j] = __float2bfloat16(f[j] - __bfloat162float(h[j]));
    }
    *(ushort4*)(Xh + i) = *(ushort4*)h;
    *(ushort4*)(Xl + i) = *(ushort4*)l;
}

// -------- Ds = skewed X2·X2^T via 3-term split-bf16 MFMA; Ds[r][(c-r)&4095].
// Epilogue: LDS transpose (2 phases of 64 rows) -> row-contiguous dwordx4 stores.
__global__ __launch_bounds__(256)
void k_gemm_d(const __hip_bfloat16* __restrict__ Xh,
              const __hip_bfloat16* __restrict__ Xl, float* __restrict__ Ds) {
    const int t = threadIdx.x;
    const int wave = t >> 6, lane = t & 63;
    const int quad = lane >> 4, l16 = lane & 15;
    const int bmB = blockIdx.x * 128;          // block row base
    const int bm = bmB + wave * 32;            // wave row base
    const int bn = blockIdx.y * 128;
    f32x4 acc[2][8] = {};
    for (int k0 = 0; k0 < CDIM; k0 += 32) {
        const int kq = k0 + quad * 8;
        bf16x8 ah[2], al[2], bh[8], bl[8];
        #pragma unroll
        for (int mi = 0; mi < 2; ++mi) {
            const size_t r = (size_t)(bm + mi * 16 + l16) * CDIM + kq;
            ah[mi] = *(const bf16x8*)(Xh + r);
            al[mi] = *(const bf16x8*)(Xl + r);
        }
        #pragma unroll
        for (int nf = 0; nf < 8; ++nf) {
            const size_t r = (size_t)(bn + nf * 16 + l16) * CDIM + kq;
            bh[nf] = *(const bf16x8*)(Xh + r);
            bl[nf] = *(const bf16x8*)(Xl + r);
        }
        #pragma unroll
        for (int mi = 0; mi < 2; ++mi)
            #pragma unroll
            for (int nf = 0; nf < 8; ++nf) {
                acc[mi][nf] = __builtin_amdgcn_mfma_f32_16x16x32_bf16(ah[mi], bh[nf], acc[mi][nf], 0, 0, 0);
                acc[mi][nf] = __builtin_amdgcn_mfma_f32_16x16x32_bf16(ah[mi], bl[nf], acc[mi][nf], 0, 0, 0);
                acc[mi][nf] = __builtin_amdgcn_mfma_f32_16x16x32_bf16(al[mi], bh[nf], acc[mi][nf], 0, 0, 0);
            }
    }

    __shared__ float sd[64][132];
    const int s = t & 31;            // lane within 32-lane row group
    #pragma unroll
    for (int ph = 0; ph < 2; ++ph) {
        __syncthreads();
        if ((wave >> 1) == ph) {
            const int rbase = (wave & 1) * 32;
            #pragma unroll
            for (int mi = 0; mi < 2; ++mi)
                #pragma unroll
                for (int nf = 0; nf < 8; ++nf)
                    #pragma unroll
                    for (int r = 0; r < 4; ++r)
                        sd[rbase + mi * 16 + quad * 4 + r][nf * 16 + l16] = acc[mi][nf][r];
        }
        __syncthreads();
        #pragma unroll
        for (int iter = 0; iter < 8; ++iter) {
            const int rl   = iter * 8 + (t >> 5);       // 0..63
            const int grow = bmB + ph * 64 + rl;
            const int d0   = (bn - grow) & (LDIM - 1);
            float* rowp = Ds + (size_t)grow * LDIM;
            const int a = grow & 3;                     // head scalar count
            if (d0 <= LDIM - 128) {
                if (a == 0) {
                    *(f32x4*)(rowp + d0 + 4 * s) = *(const f32x4*)&sd[rl][4 * s];
                } else {
                    const f32x4 lo = *(const f32x4*)&sd[rl][4 * s];
                    const f32x4 hi = *(const f32x4*)&sd[rl][4 * s + 4];  // s=31 reads pad, masked below
                    f32x4 ov;
                    if (a == 1)      { ov[0] = lo[1]; ov[1] = lo[2]; ov[2] = lo[3]; ov[3] = hi[0]; }
                    else if (a == 2) { ov[0] = lo[2]; ov[1] = lo[3]; ov[2] = hi[0]; ov[3] = hi[1]; }
                    else             { ov[0] = lo[3]; ov[1] = hi[0]; ov[2] = hi[1]; ov[3] = hi[2]; }
                    if (s < 31)
                        *(f32x4*)(rowp + d0 + a + 4 * s) = ov;
                    else {
                        for (int k = 0; k < a; ++k)        rowp[d0 + k] = sd[rl][k];
                        for (int k = 0; k < 4 - a; ++k)    rowp[d0 + 124 + a + k] = sd[rl][124 + a + k];
                    }
                }
            } else {
                #pragma unroll
                for (int k = 0; k < 4; ++k) {
                    const int col = 4 * s + k;
                    rowp[(d0 + col) & (LDIM - 1)] = sd[rl][col];
                }
            }
        }
    }
}

// ---------------- invn[l] = 1/max(sqrt(sum diag-neigh),eps); diag = Ds[.][0]
__global__ void k_invnorm(const float* __restrict__ Ds, float* __restrict__ invn) {
    const int l = blockIdx.x * 256 + threadIdx.x;
    const int ly = l >> 6, lx = l & 63;
    float s = 0.f;
    #pragma unroll
    for (int ty = -1; ty <= 1; ++ty)
        #pragma unroll
        for (int tx = -1; tx <= 1; ++tx) {
            if ((unsigned)(ly + ty) < 64u && (unsigned)(lx + tx) < 64u) {
                const int q = l + ty * Ww + tx;
                s += Ds[(size_t)q * LDIM];
            }
        }
    invn[l] = 1.0f / fmaxf(sqrtf(s), 1e-4f);
}

// ---- G[x,l] = sum_t D[x+t,l+t] read vertically from skewed Ds.
__global__ __launch_bounds__(256)
void k_gdiag(const float* __restrict__ Ds, float* __restrict__ G) {
    constexpr int T = 8;
    const int d0 = (blockIdx.x * 256 + threadIdx.x) * 4;
    const int x0 = blockIdx.y * T;
    const int xyc = x0 >> 6;
    const int xxb = x0 & 63;
    float acc[T][4] = {};
    #pragma unroll
    for (int c = 0; c < 3; ++c) {
        const int bc = c * 64 - 65;          // -65, -1, 63
        const int ty = c - 1;
        if ((unsigned)(xyc + ty) >= 64u) continue;
        float w[T + 2][4];
        #pragma unroll
        for (int u = 0; u < T + 2; ++u) {
            const int r = x0 + bc + u;
            if ((unsigned)r < (unsigned)LDIM) {
                const f32x4 v = *(const f32x4*)(Ds + (size_t)r * LDIM + d0);
                w[u][0] = v.x; w[u][1] = v.y; w[u][2] = v.z; w[u][3] = v.w;
            } else {
                w[u][0] = w[u][1] = w[u][2] = w[u][3] = 0.f;
            }
        }
        #pragma unroll
        for (int i = 0; i < T; ++i) {
            const int px = xxb + i;
            const int p  = x0 + i;
            #pragma unroll
            for (int j = 0; j < 4; ++j) {
                const int l  = (p + d0 + j) & (LDIM - 1);
                const int ly = l >> 6, lx = l & 63;
                if ((unsigned)(ly + ty) < 64u) {
                    float sv = acc[i][j];
                    if (px > 0 && lx > 0)   sv += w[i][j];
                    sv += w[i + 1][j];
                    if (px < 63 && lx < 63) sv += w[i + 2][j];
                    acc[i][j] = sv;
                }
            }
        }
    }
    #pragma unroll
    for (int i = 0; i < T; ++i) {
        const int x = x0 + i;
        const int l0i = (x + d0) & (LDIM - 1);
        float* base = G + (size_t)x * LDIM;
        if (l0i <= LDIM - 4) {
            if (!(l0i & 1)) {
                *(float2*)(base + l0i)     = make_float2(acc[i][0], acc[i][1]);
                *(float2*)(base + l0i + 2) = make_float2(acc[i][2], acc[i][3]);
            } else {
                base[l0i] = acc[i][0];
                *(float2*)(base + l0i + 1) = make_float2(acc[i][1], acc[i][2]);
                base[l0i + 3] = acc[i][3];
            }
        } else {
            #pragma unroll
            for (int j = 0; j < 4; ++j)
                base[(l0i + j) & (LDIM - 1)] = acc[i][j];
        }
    }
}

// ------- P[x,l] = (90/cnt)*invn[l]*sum_s G[x+s,l]; 4-col float4 vectorized.
// Output stored SKEWED: Ps[x][(l-x)&4095] = P[x][l]. Row softmax stats too.
__global__ __launch_bounds__(256)
void k_pool_stats(const float* __restrict__ G, const float* __restrict__ invn,
                  float* __restrict__ Ps, float* __restrict__ rowm,
                  float* __restrict__ rowrz) {
    constexpr int T = 8;
    const int x0 = blockIdx.x * T;
    const int t  = threadIdx.x;
    const int xyc = x0 >> 6;
    const int xxb = x0 & 63;
    const int cy = 1 + (xyc > 0) + (xyc < 63);
    float sc[T];
    #pragma unroll
    for (int i = 0; i < T; ++i) {
        const int xx = xxb + i;
        sc[i] = 90.0f / (float)(cy * (1 + (xx > 0) + (xx < 63)));
    }
    float m[T], Z[T];
    #pragma unroll
    for (int i = 0; i < T; ++i) { m[i] = -1e30f; Z[i] = 0.f; }

    for (int ch = 0; ch < 4; ++ch) {
        const int l0 = ch * 1024 + t * 4;
        const f32x4 inl = *(const f32x4*)(invn + l0);
        f32x4 acc[T];
        #pragma unroll
        for (int i = 0; i < T; ++i) acc[i] = (f32x4){0.f, 0.f, 0.f, 0.f};
        #pragma unroll
        for (int c = 0; c < 3; ++c) {
            const int bc = c * 64 - 65;
            const int ty = c - 1;
            if ((unsigned)(xyc + ty) >= 64u) continue;
            f32x4 w[T + 2];
            #pragma unroll
            for (int u = 0; u < T + 2; ++u) {
                const int r = x0 + bc + u;
                w[u] = ((unsigned)r < (unsigned)LDIM)
                         ? *(const f32x4*)(G + (size_t)r * LDIM + l0)
                         : (f32x4){0.f, 0.f, 0.f, 0.f};
            }
            #pragma unroll
            for (int i = 0; i < T; ++i) {
                const int xx = xxb + i;
                if (xx > 0)  acc[i] += w[i];
                acc[i] += w[i + 1];
                if (xx < 63) acc[i] += w[i + 2];
            }
        }
        #pragma unroll
        for (int i = 0; i < T; ++i) {
            const f32x4 p = acc[i] * sc[i] * inl;
            const int x = x0 + i;
            const int c0 = (l0 - x) & (LDIM - 1);
            float* base = Ps + (size_t)x * LDIM;
            if (c0 <= LDIM - 4) {
                if (!(c0 & 1)) {
                    *(float2*)(base + c0)     = make_float2(p.x, p.y);
                    *(float2*)(base + c0 + 2) = make_float2(p.z, p.w);
                } else {
                    base[c0] = p.x;
                    *(float2*)(base + c0 + 1) = make_float2(p.y, p.z);
                    base[c0 + 3] = p.w;
                }
            } else {
                base[c0] = p.x;
                base[(c0 + 1) & (LDIM - 1)] = p.y;
                base[(c0 + 2) & (LDIM - 1)] = p.z;
                base[(c0 + 3) & (LDIM - 1)] = p.w;
            }
            const float mx4 = fmaxf(fmaxf(p.x, p.y), fmaxf(p.z, p.w));
            const float nm = fmaxf(m[i], mx4);
            Z[i] = Z[i] * __expf(m[i] - nm)
                 + __expf(p.x - nm) + __expf(p.y - nm)
                 + __expf(p.z - nm) + __expf(p.w - nm);
            m[i] = nm;
        }
    }
    __shared__ float sm[256], sz[256];
    for (int i = 0; i < T; ++i) {
        __syncthreads();
        sm[t] = m[i]; sz[t] = Z[i];
        __syncthreads();
        for (int off = 128; off > 0; off >>= 1) {
            if (t < off) {
                const float m2 = sm[t + off], z2 = sz[t + off];
                const float nm = fmaxf(sm[t], m2);
                sz[t] = sz[t] * __expf(sm[t] - nm) + z2 * __expf(m2 - nm);
                sm[t] = nm;
            }
            __syncthreads();
        }
        if (t == 0) { rowm[x0 + i] = sm[0]; rowrz[x0 + i] = 1.0f / sz[0]; }
    }
}

// ---- X1 [4096][128] fp32 -> X1T [128][4096] bf16 (LDS-tiled transpose)
// Launched AFTER k_pool_stats: X1T region overlaps G's tail in buf2.
__global__ __launch_bounds__(256)
void k_x1t(const float* __restrict__ X1, __hip_bfloat16* __restrict__ X1T) {
    __shared__ float tile[32][132];
    const int k0 = blockIdx.x * 32;
    const int t  = threadIdx.x;
    const int kr = t >> 3;
    const int c0 = (t & 7) * 16;
    #pragma unroll
    for (int j = 0; j < 4; ++j) {
        const float4 v = *(const float4*)(X1 + (size_t)(k0 + kr) * CDIM + c0 + 4 * j);
        tile[kr][c0 + 4 * j + 0] = v.x;
        tile[kr][c0 + 4 * j + 1] = v.y;
        tile[kr][c0 + 4 * j + 2] = v.z;
        tile[kr][c0 + 4 * j + 3] = v.w;
    }
    __syncthreads();
    const int c  = t >> 1;
    const int kh = (t & 1) * 16;
    __hip_bfloat16 outv[16];
    #pragma unroll
    for (int j = 0; j < 16; ++j)
        outv[j] = __float2bfloat16(tile[kh + j][c]);
    *(ushort4*)(X1T + (size_t)c * LDIM + k0 + kh)      = *(ushort4*)(outv);
    *(ushort4*)(X1T + (size_t)c * LDIM + k0 + kh + 4)  = *(ushort4*)(outv + 4);
    *(ushort4*)(X1T + (size_t)c * LDIM + k0 + kh + 8)  = *(ushort4*)(outv + 8);
    *(ushort4*)(X1T + (size_t)c * LDIM + k0 + kh + 12) = *(ushort4*)(outv + 12);
}

// ---- A2[p,q] = sum_t exp(P[p+t,q+t]-m)*rz. Reads skewed Ps vertically.
__global__ __launch_bounds__(256)
void k_att2(const float* __restrict__ Ps, const float* __restrict__ rowm,
            const float* __restrict__ rowrz, __hip_bfloat16* __restrict__ A2) {
    constexpr int T = 8;
    const int d0 = (blockIdx.x * 256 + threadIdx.x) * 4;
    const int p0 = blockIdx.y * T;
    const int pyc = p0 >> 6;
    const int pxb = p0 & 63;
    float acc[T][4] = {};
    #pragma unroll
    for (int c = 0; c < 3; ++c) {
        const int bc = c * 64 - 65;          // -65, -1, 63
        const int ty = c - 1;
        if ((unsigned)(pyc + ty) >= 64u) continue;
        float e[T + 2][4];
        #pragma unroll
        for (int u = 0; u < T + 2; ++u) {
            const int r = p0 + bc + u;
            if ((unsigned)r < (unsigned)LDIM) {
                const f32x4 w = *(const f32x4*)(Ps + (size_t)r * LDIM + d0);
                const float mr = rowm[r], rzr = rowrz[r];
                e[u][0] = __expf(w.x - mr) * rzr;
                e[u][1] = __expf(w.y - mr) * rzr;
                e[u][2] = __expf(w.z - mr) * rzr;
                e[u][3] = __expf(w.w - mr) * rzr;
            } else {
                e[u][0] = e[u][1] = e[u][2] = e[u][3] = 0.f;
            }
        }
        #pragma unroll
        for (int i = 0; i < T; ++i) {
            const int px = pxb + i;
            const int p  = p0 + i;
            #pragma unroll
            for (int j = 0; j < 4; ++j) {
                const int q  = (p + d0 + j) & (LDIM - 1);
                const int qy = q >> 6, qx = q & 63;
                if ((unsigned)(qy + ty) < 64u) {
                    float sv = acc[i][j];
                    if (px > 0 && qx > 0)   sv += e[i][j];
                    sv += e[i + 1][j];
                    if (px < 63 && qx < 63) sv += e[i + 2][j];
                    acc[i][j] = sv;
                }
            }
        }
    }
    #pragma unroll
    for (int i = 0; i < T; ++i) {
        const int p = p0 + i;
        const int q0i = (p + d0) & (LDIM - 1);
        union { __hip_bfloat16 h[4]; unsigned short us[4]; unsigned int ui[2]; } cv;
        #pragma unroll
        for (int j = 0; j < 4; ++j) cv.h[j] = __float2bfloat16(acc[i][j]);
        unsigned short* bp = (unsigned short*)(A2 + (size_t)p * LDIM);
        if (q0i <= LDIM - 4) {
            if (!(q0i & 1)) {
                *(unsigned int*)(bp + q0i)     = cv.ui[0];
                *(unsigned int*)(bp + q0i + 2) = cv.ui[1];
            } else {
                bp[q0i] = cv.us[0];
                *(unsigned int*)(bp + q0i + 1) =
                    (unsigned int)cv.us[1] | ((unsigned int)cv.us[2] << 16);
                bp[q0i + 3] = cv.us[3];
            }
        } else {
            #pragma unroll
            for (int j = 0; j < 4; ++j)
                bp[(q0i + j) & (LDIM - 1)] = cv.us[j];
        }
    }
}

// ---------------- Y += A2 @ X1 (bf16 MFMA, split-K=8, atomic f32 epilogue)
__global__ __launch_bounds__(256)
void k_gemm_y(const __hip_bfloat16* __restrict__ A2b,
              const __hip_bfloat16* __restrict__ X1T, float* __restrict__ Y) {
    const int t = threadIdx.x;
    const int wave = t >> 6, lane = t & 63;
    const int quad = lane >> 4, l16 = lane & 15;
    const int bm = blockIdx.x * 128 + wave * 32;
    const int kc = blockIdx.y * 512;
    f32x4 acc[2][8] = {};
    for (int ks = 0; ks < 512; ks += 32) {
        const int kq = kc + ks + quad * 8;
        bf16x8 a[2], b[8];
        #pragma unroll
        for (int mi = 0; mi < 2; ++mi)
            a[mi] = *(const bf16x8*)(A2b + (size_t)(bm + mi * 16 + l16) * LDIM + kq);
        #pragma unroll
        for (int nf = 0; nf < 8; ++nf)
            b[nf] = *(const bf16x8*)(X1T + (size_t)(nf * 16 + l16) * LDIM + kq);
        #pragma unroll
        for (int mi = 0; mi < 2; ++mi)
            #pragma unroll
            for (int nf = 0; nf < 8; ++nf)
                acc[mi][nf] = __builtin_amdgcn_mfma_f32_16x16x32_bf16(a[mi], b[nf], acc[mi][nf], 0, 0, 0);
    }
    #pragma unroll
    for (int mi = 0; mi < 2; ++mi)
        #pragma unroll
        for (int nf = 0; nf < 8; ++nf)
            #pragma unroll
            for (int r = 0; r < 4; ++r)
                atomicAdd(Y + (size_t)(bm + mi * 16 + quad * 4 + r) * CDIM + nf * 16 + l16,
                          acc[mi][nf][r]);
}

extern "C" void kernel_launch(void* const* d_in, const int* in_sizes, int n_in,
                              void* d_out, int out_size, void* d_ws, size_t ws_size,
                              hipStream_t stream) {
    const float* x1 = (const float*)d_in[0];
    const float* x2 = (const float*)d_in[1];
    float* out = (float*)d_out;

    const size_t MATB = (size_t)LDIM * LDIM * sizeof(float);   // 64 MB
    char* ws = (char*)d_ws;
    float* buf1  = (float*)ws;                         // Ds, then Ps (fp32)
    char*  buf2c = ws + MATB;                          // multi-use 64 MB
    float* buf2  = (float*)buf2c;                      // G (fp32)
    __hip_bfloat16* X2h = (__hip_bfloat16*)buf2c;                    // 1 MB
    __hip_bfloat16* X2l = (__hip_bfloat16*)(buf2c + (size_t)LDIM * CDIM * 2);
    __hip_bfloat16* A2b = (__hip_bfloat16*)buf2c;                    // 32 MB
    __hip_bfloat16* X1T = (__hip_bfloat16*)(buf2c + MATB / 2);       // 1 MB
    float* invn  = (float*)(ws + 2 * MATB);
    float* rowm  = invn + LDIM;
    float* rowrz = rowm + LDIM;

    const int B = in_sizes[0] / (LDIM * CDIM);

    hipMemsetAsync(d_out, 0, (size_t)out_size * sizeof(float), stream);

    for (int b = 0; b < B; ++b) {
        const float* X2b_ = x2 + (size_t)b * LDIM * CDIM;
        const float* X1b_ = x1 + (size_t)b * LDIM * CDIM;
        float* Yb = out + (size_t)b * LDIM * CDIM;

        k_split     <<<LDIM * CDIM / 1024, 256, 0, stream>>>(X2b_, X2h, X2l);
        k_gemm_d    <<<dim3(LDIM / 128, LDIM / 128), 256, 0, stream>>>(X2h, X2l, buf1);
        k_invnorm   <<<LDIM / 256, 256, 0, stream>>>(buf1, invn);
        k_gdiag     <<<dim3(LDIM / 1024, LDIM / 8), 256, 0, stream>>>(buf1, buf2);
        k_pool_stats<<<LDIM / 8, 256, 0, stream>>>(buf2, invn, buf1, rowm, rowrz);
        k_x1t       <<<LDIM / 32, 256, 0, stream>>>(X1b_, X1T);
        k_att2      <<<dim3(LDIM / 1024, LDIM / 8), 256, 0, stream>>>(buf1, rowm, rowrz, A2b);
        k_gemm_y    <<<dim3(LDIM / 128, 8), 256, 0, stream>>>(A2b, X1T, Yb);
    }
}

// Round 10
// 482.323 us; speedup vs baseline: 1.0470x; 1.0470x over previous
//
#include <hip/hip_runtime.h>
#include <hip/hip_bf16.h>
#include <math.h>

// AtnConv (contextual attention) B=2, H=W=64, C=128, k=3.
// Score path fp32: Ds = skewed X2·X2^T (split-bf16 MFMA, Ds[r][(c-r)&4095],
// scalar skew stores); invn; G = 9-tap diag stencil (vertical float4 reads
// from skew); Ps = pooled logits (skewed) + row softmax stats; A2 = diag
// stencil of softmax(Ps) bf16; Y = A2 @ X1 bf16 MFMA split-K.
// Batch merge: if ws_size >= 2*B*64MB + stats, both batches run in ONE set of
// dispatches via blockIdx.z; else per-batch fallback (identical to R7 flow).
// NOTE: k_x1t after k_pool_stats — X1T region overlaps G within buf2.

constexpr int Hh = 64;
constexpr int Ww = 64;
constexpr int CDIM = 128;
constexpr int LDIM = Hh * Ww;   // 4096

typedef __attribute__((ext_vector_type(8))) short bf16x8;
typedef __attribute__((ext_vector_type(4))) float f32x4;

// --------------------------------------------- split X2 into bf16 hi/lo parts
__global__ __launch_bounds__(256)
void k_split(const float* __restrict__ X, __hip_bfloat16* __restrict__ Xh,
             __hip_bfloat16* __restrict__ Xl, size_t xzs, size_t hzs) {
    const size_t z = blockIdx.z;
    const float* Xz = X + z * xzs;
    __hip_bfloat16* Xhz = Xh + z * hzs;
    __hip_bfloat16* Xlz = Xl + z * hzs;
    const int i = (blockIdx.x * 256 + threadIdx.x) * 4;
    const float4 v = *(const float4*)(Xz + i);
    __hip_bfloat16 h[4], l[4];
    const float f[4] = {v.x, v.y, v.z, v.w};
    #pragma unroll
    for (int j = 0; j < 4; ++j) {
        h[j] = __float2bfloat16(f[j]);
        l[j] = __float2bfloat16(f[j] - __bfloat162float(h[j]));
    }
    *(ushort4*)(Xhz + i) = *(ushort4*)h;
    *(ushort4*)(Xlz + i) = *(ushort4*)l;
}

// -------- Ds = skewed X2·X2^T via 3-term split-bf16 MFMA; Ds[r][(c-r)&4095]
__global__ __launch_bounds__(256)
void k_gemm_d(const __hip_bfloat16* __restrict__ Xh,
              const __hip_bfloat16* __restrict__ Xl, float* __restrict__ Ds,
              size_t hzs, size_t dzs) {
    const size_t z = blockIdx.z;
    const __hip_bfloat16* Xhz = Xh + z * hzs;
    const __hip_bfloat16* Xlz = Xl + z * hzs;
    float* Dsz = Ds + z * dzs;
    const int t = threadIdx.x;
    const int wave = t >> 6, lane = t & 63;
    const int quad = lane >> 4, l16 = lane & 15;
    const int bm = blockIdx.x * 128 + wave * 32;
    const int bn = blockIdx.y * 128;
    f32x4 acc[2][8] = {};
    for (int k0 = 0; k0 < CDIM; k0 += 32) {
        const int kq = k0 + quad * 8;
        bf16x8 ah[2], al[2], bh[8], bl[8];
        #pragma unroll
        for (int mi = 0; mi < 2; ++mi) {
            const size_t r = (size_t)(bm + mi * 16 + l16) * CDIM + kq;
            ah[mi] = *(const bf16x8*)(Xhz + r);
            al[mi] = *(const bf16x8*)(Xlz + r);
        }
        #pragma unroll
        for (int nf = 0; nf < 8; ++nf) {
            const size_t r = (size_t)(bn + nf * 16 + l16) * CDIM + kq;
            bh[nf] = *(const bf16x8*)(Xhz + r);
            bl[nf] = *(const bf16x8*)(Xlz + r);
        }
        #pragma unroll
        for (int mi = 0; mi < 2; ++mi)
            #pragma unroll
            for (int nf = 0; nf < 8; ++nf) {
                acc[mi][nf] = __builtin_amdgcn_mfma_f32_16x16x32_bf16(ah[mi], bh[nf], acc[mi][nf], 0, 0, 0);
                acc[mi][nf] = __builtin_amdgcn_mfma_f32_16x16x32_bf16(ah[mi], bl[nf], acc[mi][nf], 0, 0, 0);
                acc[mi][nf] = __builtin_amdgcn_mfma_f32_16x16x32_bf16(al[mi], bh[nf], acc[mi][nf], 0, 0, 0);
            }
    }
    #pragma unroll
    for (int mi = 0; mi < 2; ++mi)
        #pragma unroll
        for (int nf = 0; nf < 8; ++nf) {
            const int row = bm + mi * 16 + quad * 4;
            const int col = bn + nf * 16 + l16;
            #pragma unroll
            for (int r = 0; r < 4; ++r)
                Dsz[(size_t)(row + r) * LDIM + ((col - row - r) & (LDIM - 1))] = acc[mi][nf][r];
        }
}

// ---------------- invn[l] = 1/max(sqrt(sum diag-neigh),eps); diag = Ds[.][0]
__global__ void k_invnorm(const float* __restrict__ Ds, float* __restrict__ invn,
                          size_t dzs, size_t szs) {
    const size_t z = blockIdx.z;
    const float* Dsz = Ds + z * dzs;
    float* invnz = invn + z * szs;
    const int l = blockIdx.x * 256 + threadIdx.x;
    const int ly = l >> 6, lx = l & 63;
    float s = 0.f;
    #pragma unroll
    for (int ty = -1; ty <= 1; ++ty)
        #pragma unroll
        for (int tx = -1; tx <= 1; ++tx) {
            if ((unsigned)(ly + ty) < 64u && (unsigned)(lx + tx) < 64u) {
                const int q = l + ty * Ww + tx;
                s += Dsz[(size_t)q * LDIM];
            }
        }
    invnz[l] = 1.0f / fmaxf(sqrtf(s), 1e-4f);
}

// ---- G[x,l] = sum_t D[x+t,l+t] read vertically from skewed Ds.
__global__ __launch_bounds__(256)
void k_gdiag(const float* __restrict__ Ds, float* __restrict__ G,
             size_t dzs, size_t gzs) {
    const size_t z = blockIdx.z;
    const float* Dsz = Ds + z * dzs;
    float* Gz = G + z * gzs;
    constexpr int T = 8;
    const int d0 = (blockIdx.x * 256 + threadIdx.x) * 4;
    const int x0 = blockIdx.y * T;
    const int xyc = x0 >> 6;
    const int xxb = x0 & 63;
    float acc[T][4] = {};
    #pragma unroll
    for (int c = 0; c < 3; ++c) {
        const int bc = c * 64 - 65;          // -65, -1, 63
        const int ty = c - 1;
        if ((unsigned)(xyc + ty) >= 64u) continue;
        float w[T + 2][4];
        #pragma unroll
        for (int u = 0; u < T + 2; ++u) {
            const int r = x0 + bc + u;
            if ((unsigned)r < (unsigned)LDIM) {
                const f32x4 v = *(const f32x4*)(Dsz + (size_t)r * LDIM + d0);
                w[u][0] = v.x; w[u][1] = v.y; w[u][2] = v.z; w[u][3] = v.w;
            } else {
                w[u][0] = w[u][1] = w[u][2] = w[u][3] = 0.f;
            }
        }
        #pragma unroll
        for (int i = 0; i < T; ++i) {
            const int px = xxb + i;
            const int p  = x0 + i;
            #pragma unroll
            for (int j = 0; j < 4; ++j) {
                const int l  = (p + d0 + j) & (LDIM - 1);
                const int ly = l >> 6, lx = l & 63;
                if ((unsigned)(ly + ty) < 64u) {
                    float sv = acc[i][j];
                    if (px > 0 && lx > 0)   sv += w[i][j];
                    sv += w[i + 1][j];
                    if (px < 63 && lx < 63) sv += w[i + 2][j];
                    acc[i][j] = sv;
                }
            }
        }
    }
    #pragma unroll
    for (int i = 0; i < T; ++i) {
        const int x = x0 + i;
        const int l0i = (x + d0) & (LDIM - 1);
        float* base = Gz + (size_t)x * LDIM;
        if (l0i <= LDIM - 4) {
            if (!(l0i & 1)) {
                *(float2*)(base + l0i)     = make_float2(acc[i][0], acc[i][1]);
                *(float2*)(base + l0i + 2) = make_float2(acc[i][2], acc[i][3]);
            } else {
                base[l0i] = acc[i][0];
                *(float2*)(base + l0i + 1) = make_float2(acc[i][1], acc[i][2]);
                base[l0i + 3] = acc[i][3];
            }
        } else {
            #pragma unroll
            for (int j = 0; j < 4; ++j)
                base[(l0i + j) & (LDIM - 1)] = acc[i][j];
        }
    }
}

// ------- P[x,l] = (90/cnt)*invn[l]*sum_s G[x+s,l]; 4-col float4 vectorized.
// Output stored SKEWED: Ps[x][(l-x)&4095] = P[x][l]. Row softmax stats too.
__global__ __launch_bounds__(256)
void k_pool_stats(const float* __restrict__ G, const float* __restrict__ invn,
                  float* __restrict__ Ps, float* __restrict__ rowm,
                  float* __restrict__ rowrz, size_t gzs, size_t pzs, size_t szs) {
    const size_t z = blockIdx.z;
    const float* Gz = G + z * gzs;
    const float* invnz = invn + z * szs;
    float* Psz = Ps + z * pzs;
    float* rowmz = rowm + z * szs;
    float* rowrzz = rowrz + z * szs;
    constexpr int T = 8;
    const int x0 = blockIdx.x * T;
    const int t  = threadIdx.x;
    const int xyc = x0 >> 6;
    const int xxb = x0 & 63;
    const int cy = 1 + (xyc > 0) + (xyc < 63);
    float sc[T];
    #pragma unroll
    for (int i = 0; i < T; ++i) {
        const int xx = xxb + i;
        sc[i] = 90.0f / (float)(cy * (1 + (xx > 0) + (xx < 63)));
    }
    float m[T], Z[T];
    #pragma unroll
    for (int i = 0; i < T; ++i) { m[i] = -1e30f; Z[i] = 0.f; }

    for (int ch = 0; ch < 4; ++ch) {
        const int l0 = ch * 1024 + t * 4;
        const f32x4 inl = *(const f32x4*)(invnz + l0);
        f32x4 acc[T];
        #pragma unroll
        for (int i = 0; i < T; ++i) acc[i] = (f32x4){0.f, 0.f, 0.f, 0.f};
        #pragma unroll
        for (int c = 0; c < 3; ++c) {
            const int bc = c * 64 - 65;
            const int ty = c - 1;
            if ((unsigned)(xyc + ty) >= 64u) continue;
            f32x4 w[T + 2];
            #pragma unroll
            for (int u = 0; u < T + 2; ++u) {
                const int r = x0 + bc + u;
                w[u] = ((unsigned)r < (unsigned)LDIM)
                         ? *(const f32x4*)(Gz + (size_t)r * LDIM + l0)
                         : (f32x4){0.f, 0.f, 0.f, 0.f};
            }
            #pragma unroll
            for (int i = 0; i < T; ++i) {
                const int xx = xxb + i;
                if (xx > 0)  acc[i] += w[i];
                acc[i] += w[i + 1];
                if (xx < 63) acc[i] += w[i + 2];
            }
        }
        #pragma unroll
        for (int i = 0; i < T; ++i) {
            const f32x4 p = acc[i] * sc[i] * inl;
            const int x = x0 + i;
            const int c0 = (l0 - x) & (LDIM - 1);
            float* base = Psz + (size_t)x * LDIM;
            if (c0 <= LDIM - 4) {
                if (!(c0 & 1)) {
                    *(float2*)(base + c0)     = make_float2(p.x, p.y);
                    *(float2*)(base + c0 + 2) = make_float2(p.z, p.w);
                } else {
                    base[c0] = p.x;
                    *(float2*)(base + c0 + 1) = make_float2(p.y, p.z);
                    base[c0 + 3] = p.w;
                }
            } else {
                base[c0] = p.x;
                base[(c0 + 1) & (LDIM - 1)] = p.y;
                base[(c0 + 2) & (LDIM - 1)] = p.z;
                base[(c0 + 3) & (LDIM - 1)] = p.w;
            }
            const float mx4 = fmaxf(fmaxf(p.x, p.y), fmaxf(p.z, p.w));
            const float nm = fmaxf(m[i], mx4);
            Z[i] = Z[i] * __expf(m[i] - nm)
                 + __expf(p.x - nm) + __expf(p.y - nm)
                 + __expf(p.z - nm) + __expf(p.w - nm);
            m[i] = nm;
        }
    }
    __shared__ float sm[256], sz[256];
    for (int i = 0; i < T; ++i) {
        __syncthreads();
        sm[t] = m[i]; sz[t] = Z[i];
        __syncthreads();
        for (int off = 128; off > 0; off >>= 1) {
            if (t < off) {
                const float m2 = sm[t + off], z2 = sz[t + off];
                const float nm = fmaxf(sm[t], m2);
                sz[t] = sz[t] * __expf(sm[t] - nm) + z2 * __expf(m2 - nm);
                sm[t] = nm;
            }
            __syncthreads();
        }
        if (t == 0) { rowmz[x0 + i] = sm[0]; rowrzz[x0 + i] = 1.0f / sz[0]; }
    }
}

// ---- X1 [4096][128] fp32 -> X1T [128][4096] bf16 (LDS-tiled transpose)
__global__ __launch_bounds__(256)
void k_x1t(const float* __restrict__ X1, __hip_bfloat16* __restrict__ X1T,
           size_t xzs, size_t tzs) {
    const size_t z = blockIdx.z;
    const float* X1z = X1 + z * xzs;
    __hip_bfloat16* X1Tz = X1T + z * tzs;
    __shared__ float tile[32][132];
    const int k0 = blockIdx.x * 32;
    const int t  = threadIdx.x;
    const int kr = t >> 3;
    const int c0 = (t & 7) * 16;
    #pragma unroll
    for (int j = 0; j < 4; ++j) {
        const float4 v = *(const float4*)(X1z + (size_t)(k0 + kr) * CDIM + c0 + 4 * j);
        tile[kr][c0 + 4 * j + 0] = v.x;
        tile[kr][c0 + 4 * j + 1] = v.y;
        tile[kr][c0 + 4 * j + 2] = v.z;
        tile[kr][c0 + 4 * j + 3] = v.w;
    }
    __syncthreads();
    const int c  = t >> 1;
    const int kh = (t & 1) * 16;
    __hip_bfloat16 outv[16];
    #pragma unroll
    for (int j = 0; j < 16; ++j)
        outv[j] = __float2bfloat16(tile[kh + j][c]);
    *(ushort4*)(X1Tz + (size_t)c * LDIM + k0 + kh)      = *(ushort4*)(outv);
    *(ushort4*)(X1Tz + (size_t)c * LDIM + k0 + kh + 4)  = *(ushort4*)(outv + 4);
    *(ushort4*)(X1Tz + (size_t)c * LDIM + k0 + kh + 8)  = *(ushort4*)(outv + 8);
    *(ushort4*)(X1Tz + (size_t)c * LDIM + k0 + kh + 12) = *(ushort4*)(outv + 12);
}

// ---- A2[p,q] = sum_t exp(P[p+t,q+t]-m)*rz. Reads skewed Ps vertically.
__global__ __launch_bounds__(256)
void k_att2(const float* __restrict__ Ps, const float* __restrict__ rowm,
            const float* __restrict__ rowrz, __hip_bfloat16* __restrict__ A2,
            size_t pzs, size_t szs, size_t azs) {
    const size_t z = blockIdx.z;
    const float* Psz = Ps + z * pzs;
    const float* rowmz = rowm + z * szs;
    const float* rowrzz = rowrz + z * szs;
    __hip_bfloat16* A2z = A2 + z * azs;
    constexpr int T = 8;
    const int d0 = (blockIdx.x * 256 + threadIdx.x) * 4;
    const int p0 = blockIdx.y * T;
    const int pyc = p0 >> 6;
    const int pxb = p0 & 63;
    float acc[T][4] = {};
    #pragma unroll
    for (int c = 0; c < 3; ++c) {
        const int bc = c * 64 - 65;          // -65, -1, 63
        const int ty = c - 1;
        if ((unsigned)(pyc + ty) >= 64u) continue;
        float e[T + 2][4];
        #pragma unroll
        for (int u = 0; u < T + 2; ++u) {
            const int r = p0 + bc + u;
            if ((unsigned)r < (unsigned)LDIM) {
                const f32x4 w = *(const f32x4*)(Psz + (size_t)r * LDIM + d0);
                const float mr = rowmz[r], rzr = rowrzz[r];
                e[u][0] = __expf(w.x - mr) * rzr;
                e[u][1] = __expf(w.y - mr) * rzr;
                e[u][2] = __expf(w.z - mr) * rzr;
                e[u][3] = __expf(w.w - mr) * rzr;
            } else {
                e[u][0] = e[u][1] = e[u][2] = e[u][3] = 0.f;
            }
        }
        #pragma unroll
        for (int i = 0; i < T; ++i) {
            const int px = pxb + i;
            const int p  = p0 + i;
            #pragma unroll
            for (int j = 0; j < 4; ++j) {
                const int q  = (p + d0 + j) & (LDIM - 1);
                const int qy = q >> 6, qx = q & 63;
                if ((unsigned)(qy + ty) < 64u) {
                    float sv = acc[i][j];
                    if (px > 0 && qx > 0)   sv += e[i][j];
                    sv += e[i + 1][j];
                    if (px < 63 && qx < 63) sv += e[i + 2][j];
                    acc[i][j] = sv;
                }
            }
        }
    }
    #pragma unroll
    for (int i = 0; i < T; ++i) {
        const int p = p0 + i;
        const int q0i = (p + d0) & (LDIM - 1);
        union { __hip_bfloat16 h[4]; unsigned short us[4]; unsigned int ui[2]; } cv;
        #pragma unroll
        for (int j = 0; j < 4; ++j) cv.h[j] = __float2bfloat16(acc[i][j]);
        unsigned short* bp = (unsigned short*)(A2z + (size_t)p * LDIM);
        if (q0i <= LDIM - 4) {
            if (!(q0i & 1)) {
                *(unsigned int*)(bp + q0i)     = cv.ui[0];
                *(unsigned int*)(bp + q0i + 2) = cv.ui[1];
            } else {
                bp[q0i] = cv.us[0];
                *(unsigned int*)(bp + q0i + 1) =
                    (unsigned int)cv.us[1] | ((unsigned int)cv.us[2] << 16);
                bp[q0i + 3] = cv.us[3];
            }
        } else {
            #pragma unroll
            for (int j = 0; j < 4; ++j)
                bp[(q0i + j) & (LDIM - 1)] = cv.us[j];
        }
    }
}

// ---------------- Y += A2 @ X1 (bf16 MFMA, split-K=8, atomic f32 epilogue)
__global__ __launch_bounds__(256)
void k_gemm_y(const __hip_bfloat16* __restrict__ A2b,
              const __hip_bfloat16* __restrict__ X1T, float* __restrict__ Y,
              size_t azs, size_t tzs, size_t yzs) {
    const size_t z = blockIdx.z;
    const __hip_bfloat16* A2z = A2b + z * azs;
    const __hip_bfloat16* X1Tz = X1T + z * tzs;
    float* Yz = Y + z * yzs;
    const int t = threadIdx.x;
    const int wave = t >> 6, lane = t & 63;
    const int quad = lane >> 4, l16 = lane & 15;
    const int bm = blockIdx.x * 128 + wave * 32;
    const int kc = blockIdx.y * 512;
    f32x4 acc[2][8] = {};
    for (int ks = 0; ks < 512; ks += 32) {
        const int kq = kc + ks + quad * 8;
        bf16x8 a[2], b[8];
        #pragma unroll
        for (int mi = 0; mi < 2; ++mi)
            a[mi] = *(const bf16x8*)(A2z + (size_t)(bm + mi * 16 + l16) * LDIM + kq);
        #pragma unroll
        for (int nf = 0; nf < 8; ++nf)
            b[nf] = *(const bf16x8*)(X1Tz + (size_t)(nf * 16 + l16) * LDIM + kq);
        #pragma unroll
        for (int mi = 0; mi < 2; ++mi)
            #pragma unroll
            for (int nf = 0; nf < 8; ++nf)
                acc[mi][nf] = __builtin_amdgcn_mfma_f32_16x16x32_bf16(a[mi], b[nf], acc[mi][nf], 0, 0, 0);
    }
    #pragma unroll
    for (int mi = 0; mi < 2; ++mi)
        #pragma unroll
        for (int nf = 0; nf < 8; ++nf)
            #pragma unroll
            for (int r = 0; r < 4; ++r)
                atomicAdd(Yz + (size_t)(bm + mi * 16 + quad * 4 + r) * CDIM + nf * 16 + l16,
                          acc[mi][nf][r]);
}

static void run_pipeline(const float* x1, const float* x2, float* out,
                         char* buf1c, char* buf2c, float* stats,
                         int nb, size_t xzs, size_t bigzs_f, size_t szs,
                         hipStream_t stream) {
    float* Ds = (float*)buf1c;                              // Ds, then Ps
    float* G  = (float*)buf2c;
    __hip_bfloat16* X2h = (__hip_bfloat16*)buf2c;
    __hip_bfloat16* X2l = X2h + (size_t)LDIM * CDIM;        // within buf2 z-slice
    __hip_bfloat16* A2b = (__hip_bfloat16*)buf2c;
    __hip_bfloat16* X1T = A2b + (size_t)LDIM * LDIM;        // buf2 z-slice + 32MB
    float* invn  = stats;
    float* rowm  = stats + LDIM;
    float* rowrz = stats + 2 * LDIM;
    const size_t hzs = 2 * bigzs_f;   // bf16 elems per z inside 64MB buf slice

    k_split     <<<dim3(LDIM * CDIM / 1024, 1, nb), 256, 0, stream>>>(x2, X2h, X2l, xzs, hzs);
    k_gemm_d    <<<dim3(LDIM / 128, LDIM / 128, nb), 256, 0, stream>>>(X2h, X2l, Ds, hzs, bigzs_f);
    k_invnorm   <<<dim3(LDIM / 256, 1, nb), 256, 0, stream>>>(Ds, invn, bigzs_f, szs);
    k_gdiag     <<<dim3(LDIM / 1024, LDIM / 8, nb), 256, 0, stream>>>(Ds, G, bigzs_f, bigzs_f);
    k_pool_stats<<<dim3(LDIM / 8, 1, nb), 256, 0, stream>>>(G, invn, Ds, rowm, rowrz,
                                                            bigzs_f, bigzs_f, szs);
    k_x1t       <<<dim3(LDIM / 32, 1, nb), 256, 0, stream>>>(x1, X1T, xzs, hzs);
    k_att2      <<<dim3(LDIM / 1024, LDIM / 8, nb), 256, 0, stream>>>(Ds, rowm, rowrz, A2b,
                                                                      bigzs_f, szs, hzs);
    k_gemm_y    <<<dim3(LDIM / 128, 8, nb), 256, 0, stream>>>(A2b, X1T, out, hzs, hzs, xzs);
}

extern "C" void kernel_launch(void* const* d_in, const int* in_sizes, int n_in,
                              void* d_out, int out_size, void* d_ws, size_t ws_size,
                              hipStream_t stream) {
    const float* x1 = (const float*)d_in[0];
    const float* x2 = (const float*)d_in[1];
    float* out = (float*)d_out;

    const size_t MATB = (size_t)LDIM * LDIM * sizeof(float);   // 64 MB
    char* ws = (char*)d_ws;
    const int B = in_sizes[0] / (LDIM * CDIM);                 // 2
    const size_t XZ = (size_t)LDIM * CDIM;                     // per-batch input elems

    hipMemsetAsync(d_out, 0, (size_t)out_size * sizeof(float), stream);

    const size_t fused_need = (size_t)2 * B * MATB + (size_t)B * 3 * LDIM * sizeof(float);
    if (ws_size >= fused_need) {
        char* buf1c = ws;                                  // B x 64MB (Ds/Ps)
        char* buf2c = ws + (size_t)B * MATB;               // B x 64MB (G/A2/X1T)
        float* stats = (float*)(ws + (size_t)2 * B * MATB);
        run_pipeline(x1, x2, out, buf1c, buf2c, stats, B,
                     XZ, (size_t)LDIM * LDIM, (size_t)3 * LDIM, stream);
    } else {
        char* buf1c = ws;
        char* buf2c = ws + MATB;
        float* stats = (float*)(ws + 2 * MATB);
        for (int b = 0; b < B; ++b)
            run_pipeline(x1 + (size_t)b * XZ, x2 + (size_t)b * XZ, out + (size_t)b * XZ,
                         buf1c, buf2c, stats, 1, 0, 0, 0, stream);
    }
}